// Round 6
// baseline (2368.466 us; speedup 1.0000x reference)
//
#include <hip/hip_runtime.h>
#include <hip/hip_bf16.h>
#include <hip/hip_cooperative_groups.h>

namespace cg = cooperative_groups;

typedef __bf16 bf16_t;
typedef __bf16 bf16x8 __attribute__((ext_vector_type(8)));
typedef float f32x4 __attribute__((ext_vector_type(4)));

#define B_DIM 8
#define LQ 1024
#define LK 1024
#define DD 512
#define NH 8
#define LB 2          // batches per chunk
#define NCH 4         // chunks

static __device__ __forceinline__ f32x4 mfma_bf16(bf16x8 a, bf16x8 b, f32x4 c) {
  return __builtin_amdgcn_mfma_f32_16x16x32_bf16(a, b, c, 0, 0, 0);
}

// async global->LDS, 16B per lane (wave-uniform LDS base + lane*16)
static __device__ __forceinline__ void gld_lds16(const bf16_t* g, bf16_t* l) {
  __builtin_amdgcn_global_load_lds(
      (const __attribute__((address_space(1))) void*)g,
      (__attribute__((address_space(3))) void*)l, 16, 0, 0);
}

// XCD-aware chunked swizzle (T1).  NOT applied to gemm_outk (R4: natural
// mapping already co-locates A-strip siblings; swizzle doubled FETCH).
static __device__ __forceinline__ int xcd_swz(int lin, int nwg) {
  return (lin & 7) * (nwg >> 3) + (lin >> 3);
}

// ---------------- one upfront conversion kernel ----------------
__global__ void cvt_all(
    const float* __restrict__ Wq, const float* __restrict__ Wk,
    const float* __restrict__ Wv, const float* __restrict__ Wp,
    const float* __restrict__ x, const float* __restrict__ st,
    const int* __restrict__ mask,
    bf16_t* __restrict__ wqb, bf16_t* __restrict__ wkb,
    bf16_t* __restrict__ wvb, bf16_t* __restrict__ wpb,
    bf16_t* __restrict__ xb, bf16_t* __restrict__ sb,
    unsigned char* __restrict__ mkb)
{
  const int g = blockIdx.x * 256 + threadIdx.x;
  if (g < 2097152) {                       // weights
    const int w = g >> 19;
    const int i = (g & 524287) * 4;
    const float* s4 = (w == 0) ? Wq : (w == 1) ? Wk : (w == 2) ? Wv : Wp;
    bf16_t* d = (w == 0) ? wqb : (w == 1) ? wkb : (w == 2) ? wvb : wpb;
    const float4 f = *(const float4*)(s4 + i);
    bf16_t* p = d + i;
    p[0] = (bf16_t)f.x; p[1] = (bf16_t)f.y; p[2] = (bf16_t)f.z; p[3] = (bf16_t)f.w;
  } else if (g < 4194304) {                // x / states
    const int h = g - 2097152;
    const int i = (h & 1048575) * 4;
    const float* s4 = (h >> 20) ? st : x;
    bf16_t* d = (h >> 20) ? sb : xb;
    const float4 f = *(const float4*)(s4 + i);
    bf16_t* p = d + i;
    p[0] = (bf16_t)f.x; p[1] = (bf16_t)f.y; p[2] = (bf16_t)f.z; p[3] = (bf16_t)f.w;
  } else {                                 // mask
    const int i = (g - 4194304) * 4;
    const int4 v = *(const int4*)(mask + i);
    uchar4 o;
    o.x = (unsigned char)v.x; o.y = (unsigned char)v.y;
    o.z = (unsigned char)v.z; o.w = (unsigned char)v.w;
    *(uchar4*)(mkb + i) = o;
  }
}

// ---------------- GEMM mainloop: BK=64, XOR-swizzled LDS ----------------
static __device__ __forceinline__ void gemm_core(
    const bf16_t* A, const bf16_t* B, int ld, int klen,
    int m0, int n0, bf16_t* As, bf16_t* Bs, f32x4 (&acc)[4][4])
{
  const int tid = threadIdx.x;
  const int wave = tid >> 6, lane = tid & 63;
  const int l15 = lane & 15, quad = lane >> 4;
  const int wm = (wave & 1) * 64, wn = (wave >> 1) * 64;

  const int r0 = tid >> 3;        // + p*32 per pass
  const int c8s = tid & 7;        // stored chunk index
  bf16_t* Asl = As + tid * 8;
  bf16_t* Bsl = Bs + tid * 8;

  for (int k0 = 0; k0 < klen; k0 += 64) {
    __syncthreads();
#pragma unroll
    for (int p = 0; p < 4; ++p) {
      const int r = r0 + p * 32;
      const int gc = ((c8s ^ (r & 7)) * 8) + k0;
      gld_lds16(A + (size_t)(m0 + r) * ld + gc, Asl + p * 2048);
      gld_lds16(B + (size_t)(n0 + r) * ld + gc, Bsl + p * 2048);
    }
    __syncthreads();  // drains vmcnt
#pragma unroll
    for (int ks = 0; ks < 2; ++ks) {
      bf16x8 af[4], bfr[4];
#pragma unroll
      for (int i = 0; i < 4; ++i) {
        const int r = wm + i * 16 + l15;
        af[i] = *(const bf16x8*)&As[(r * 8 + ((ks * 4 + quad) ^ (r & 7))) * 8];
      }
#pragma unroll
      for (int j = 0; j < 4; ++j) {
        const int r = wn + j * 16 + l15;
        bfr[j] = *(const bf16x8*)&Bs[(r * 8 + ((ks * 4 + quad) ^ (r & 7))) * 8];
      }
#pragma unroll
      for (int i = 0; i < 4; ++i)
#pragma unroll
        for (int j = 0; j < 4; ++j)
          acc[i][j] = mfma_bf16(af[i], bfr[j], acc[i][j]);
    }
  }
}

// ================= per-tile bodies (shared by coop + fallback paths) =====

// qkv: wg in [0,1536) -> role/z/tx
static __device__ __forceinline__ void qkv_tile(
    int wg, const bf16_t* xc, const bf16_t* sc,
    const bf16_t* wq, const bf16_t* wk, const bf16_t* wv,
    const float* bq, const float* bk, const float* bv,
    bf16_t* Qc, bf16_t* Kc, bf16_t* Vtc, bf16_t* As, bf16_t* Bs)
{
  const int tx = wg & 31, yy = wg >> 5;
  const int role = yy >> 4, z = yy & 15;
  const int bb = z >> 3, hh = z & 7;

  const bf16_t* A; const bf16_t* Bm; const float* bias; bf16_t* C;
  int m0, n0, ldc, bias_row;
  if (role == 0) {
    A = xc + (size_t)bb * LQ * DD; Bm = wq + (size_t)hh * DD * DD;
    bias = bq + hh * DD; C = Qc + (size_t)z * LQ * DD;
    m0 = (tx >> 2) * 128; n0 = (tx & 3) * 128; ldc = DD; bias_row = 0;
  } else if (role == 1) {
    A = sc + (size_t)bb * LK * DD; Bm = wk + (size_t)hh * DD * DD;
    bias = bk + hh * DD; C = Kc + (size_t)z * LK * DD;
    m0 = (tx >> 2) * 128; n0 = (tx & 3) * 128; ldc = DD; bias_row = 0;
  } else {
    A = wv + (size_t)hh * DD * DD; Bm = sc + (size_t)bb * LK * DD;
    bias = bv + hh * DD; C = Vtc + (size_t)z * DD * LK;
    m0 = (tx & 3) * 128; n0 = (tx >> 2) * 128; ldc = LK; bias_row = 1;
  }

  f32x4 acc[4][4];
#pragma unroll
  for (int i = 0; i < 4; ++i)
#pragma unroll
    for (int j = 0; j < 4; ++j) acc[i][j] = (f32x4){0.f, 0.f, 0.f, 0.f};

  gemm_core(A, Bm, DD, DD, m0, n0, As, Bs, acc);

  const int tid = threadIdx.x, wave = tid >> 6, lane = tid & 63;
  const int l15 = lane & 15, quad = lane >> 4;
  const int wm = (wave & 1) * 64, wn = (wave >> 1) * 64;
#pragma unroll
  for (int i = 0; i < 4; ++i)
#pragma unroll
    for (int j = 0; j < 4; ++j)
#pragma unroll
      for (int r = 0; r < 4; ++r) {
        const int row = m0 + wm + i * 16 + quad * 4 + r;
        const int col = n0 + wn + j * 16 + l15;
        const float v = acc[i][j][r] + (bias_row ? bias[row] : bias[col]);
        C[(size_t)row * ldc + col] = (bf16_t)v;
      }
}

// qk: wg in [0,1024).  rs layout: [z][ntile(8)][half(2)][LQ] f32.
static __device__ __forceinline__ void qk_tile(
    int wg, const bf16_t* Q, const bf16_t* K, const unsigned char* mc,
    bf16_t* S, float* rs, bf16_t* As, bf16_t* Bs)
{
  const int bx = wg & 7, nt = (wg >> 3) & 7, z = wg >> 6;
  const int bb = z >> 3;
  const bf16_t* Az = Q + (size_t)z * LQ * DD;
  const bf16_t* Bz = K + (size_t)z * LK * DD;
  bf16_t* Sz = S + (size_t)z * LQ * LK;
  const unsigned char* mz = mc + (size_t)bb * LQ * LK;

  const int m0 = bx * 128, n0 = nt * 128;
  f32x4 acc[4][4];
#pragma unroll
  for (int i = 0; i < 4; ++i)
#pragma unroll
    for (int j = 0; j < 4; ++j) acc[i][j] = (f32x4){0.f, 0.f, 0.f, 0.f};

  gemm_core(Az, Bz, DD, DD, m0, n0, As, Bs, acc);

  const int tid = threadIdx.x, wave = tid >> 6, lane = tid & 63;
  const int l15 = lane & 15, quad = lane >> 4;
  const int wm = (wave & 1) * 64, wn = (wave >> 1) * 64;
  float* rsz = rs + (((size_t)z * 8 + nt) * 2 + (wave >> 1)) * LQ;
  const float scale = 0.04419417382415922f;  // 1/sqrt(512)

#pragma unroll
  for (int i = 0; i < 4; ++i)
#pragma unroll
    for (int r = 0; r < 4; ++r) {
      const int row = m0 + wm + i * 16 + quad * 4 + r;
      float rsum = 0.f;
#pragma unroll
      for (int j = 0; j < 4; ++j) {
        const int col = n0 + wn + j * 16 + l15;
        const int mv = mz[(size_t)row * LK + col];
        const float p = mv ? __expf(acc[i][j][r] * scale) : 0.f;
        rsum += p;
        Sz[(size_t)row * LK + col] = (bf16_t)p;
      }
      rsum += __shfl_xor(rsum, 1);
      rsum += __shfl_xor(rsum, 2);
      rsum += __shfl_xor(rsum, 4);
      rsum += __shfl_xor(rsum, 8);
      if (l15 == 0) rsz[row] = rsum;   // block+half-owned slot, no race
    }
}

// pv: wg in [0,512)
static __device__ __forceinline__ void pv_tile(
    int wg, const bf16_t* S, const bf16_t* Vt, const float* rs,
    bf16_t* ctxc, bf16_t* As, bf16_t* Bs, float* invs)
{
  const int bx = wg & 7, by = (wg >> 3) & 3, z = wg >> 5;
  const int bb = z >> 3, hh = z & 7;
  const bf16_t* Az = S + (size_t)z * LQ * LK;
  const bf16_t* Bz = Vt + (size_t)z * DD * LK;
  bf16_t* Cz = ctxc + (size_t)bb * LQ * (NH * DD) + (size_t)hh * DD;

  const int m0 = bx * 128, n0 = by * 128;
  const int tid = threadIdx.x;
  if (tid < 128) {   // rowsum reduce for this block's 128 rows
    const float* p = rs + (size_t)z * 16 * LQ + (m0 + tid);
    float tot = 0.f;
#pragma unroll
    for (int s = 0; s < 16; ++s) tot += p[s * LQ];
    invs[tid] = 1.f / tot;
  }
  // visibility via gemm_core's internal barriers before epilogue

  f32x4 acc[4][4];
#pragma unroll
  for (int i = 0; i < 4; ++i)
#pragma unroll
    for (int j = 0; j < 4; ++j) acc[i][j] = (f32x4){0.f, 0.f, 0.f, 0.f};

  gemm_core(Az, Bz, LK, LK, m0, n0, As, Bs, acc);

  const int wave = tid >> 6, lane = tid & 63;
  const int l15 = lane & 15, quad = lane >> 4;
  const int wm = (wave & 1) * 64, wn = (wave >> 1) * 64;

#pragma unroll
  for (int i = 0; i < 4; ++i)
#pragma unroll
    for (int r = 0; r < 4; ++r) {
      const int lrow = wm + i * 16 + quad * 4 + r;
      const float iv = invs[lrow];
#pragma unroll
      for (int j = 0; j < 4; ++j) {
        const int col = n0 + wn + j * 16 + l15;
        Cz[(size_t)(m0 + lrow) * (NH * DD) + col] = (bf16_t)(acc[i][j][r] * iv);
      }
    }
}

// ================= cooperative fused chunk loop ==========================
// 1024 blocks x 256 thr = exactly 4 blocks/CU (LDS 33KB -> 4/CU; launch
// bounds cap VGPR at 128).  Replaces 12 dispatches + 11 gaps with 1 dispatch
// + 12 grid syncs.  Tile->XCD mapping identical to the split dispatches
// (t and t+1024 share t&7).  ctxb aliases xbF/sbF (chunk-3 overlay): no
// __restrict__ on those; ordering enforced by grid.sync().
__global__ __launch_bounds__(256, 4) void fused_chunks(
    const bf16_t* xbF, const bf16_t* sbF,
    const bf16_t* wq, const bf16_t* wk, const bf16_t* wv,
    const float* bq, const float* bk, const float* bv,
    const unsigned char* mkb,
    bf16_t* Qc, bf16_t* Kc, bf16_t* Vtc, bf16_t* Sb,
    float* rs, bf16_t* ctxb)
{
  cg::grid_group grid = cg::this_grid();
  __shared__ __align__(16) bf16_t As[128 * 64];
  __shared__ __align__(16) bf16_t Bs[128 * 64];
  __shared__ float invs[128];
  const int bid = blockIdx.x;

  for (int c = 0; c < NCH; ++c) {
    const bf16_t* xc = xbF + (size_t)c * (LB * LQ * DD);
    const bf16_t* sc = sbF + (size_t)c * (LB * LK * DD);
    const unsigned char* mc = mkb + (size_t)c * (LB * LQ * LK);
    bf16_t* ctxc = ctxb + (size_t)c * LB * LQ * (NH * DD);

    // stage 1: qkv (1536 tiles, persistent)
    for (int t = bid; t < 1536; t += 1024)
      qkv_tile(xcd_swz(t, 1536), xc, sc, wq, wk, wv, bq, bk, bv,
               Qc, Kc, Vtc, As, Bs);
    grid.sync();

    // stage 2: qk (1024 tiles)
    qk_tile(xcd_swz(bid, 1024), Qc, Kc, mc, Sb, rs, As, Bs);
    grid.sync();

    // stage 3: pv (512 tiles)
    if (bid < 512)
      pv_tile(xcd_swz(bid, 512), Sb, Vtc, rs, ctxc, As, Bs, invs);
    grid.sync();
  }
}

// ================= fallback standalone kernels (if coop unsupported) =====
__global__ __launch_bounds__(256, 4) void gemm_qkv(
    const bf16_t* __restrict__ xc, const bf16_t* __restrict__ sc,
    const bf16_t* __restrict__ wq, const bf16_t* __restrict__ wk,
    const bf16_t* __restrict__ wv,
    const float* __restrict__ bq, const float* __restrict__ bk,
    const float* __restrict__ bv,
    bf16_t* __restrict__ Qc, bf16_t* __restrict__ Kc, bf16_t* __restrict__ Vtc)
{
  __shared__ __align__(16) bf16_t As[128 * 64];
  __shared__ __align__(16) bf16_t Bs[128 * 64];
  const int lin = blockIdx.y * 32 + blockIdx.x;
  qkv_tile(xcd_swz(lin, 1536), xc, sc, wq, wk, wv, bq, bk, bv,
           Qc, Kc, Vtc, As, Bs);
}

__global__ __launch_bounds__(256, 4) void gemm_qk(
    const bf16_t* __restrict__ Q, const bf16_t* __restrict__ K,
    const unsigned char* __restrict__ mc, bf16_t* __restrict__ S,
    float* __restrict__ rs)
{
  __shared__ __align__(16) bf16_t As[128 * 64];
  __shared__ __align__(16) bf16_t Bs[128 * 64];
  const int lin = (blockIdx.z * 8 + blockIdx.y) * 8 + blockIdx.x;
  qk_tile(xcd_swz(lin, 1024), Q, K, mc, S, rs, As, Bs);
}

__global__ __launch_bounds__(256, 4) void gemm_pv(
    const bf16_t* __restrict__ S, const bf16_t* __restrict__ Vt,
    const float* __restrict__ rs, bf16_t* __restrict__ ctxc)
{
  __shared__ __align__(16) bf16_t As[128 * 64];
  __shared__ __align__(16) bf16_t Bs[128 * 64];
  __shared__ float invs[128];
  const int lin = (blockIdx.z * 4 + blockIdx.y) * 8 + blockIdx.x;
  pv_tile(xcd_swz(lin, 512), S, Vt, rs, ctxc, As, Bs, invs);
}

// ---------------- out-projection, split-K=4 (natural mapping) -----------
__global__ __launch_bounds__(256, 4) void gemm_outk(
    const bf16_t* __restrict__ ctx, const bf16_t* __restrict__ wp,
    float* __restrict__ partial)
{
  const int ks = blockIdx.z;
  const bf16_t* A = ctx + ks * 1024;
  const bf16_t* B = wp + ks * 1024;
  float* P = partial + (size_t)ks * B_DIM * LQ * DD;

  const int m0 = blockIdx.x * 128, n0 = blockIdx.y * 128;
  __shared__ __align__(16) bf16_t As[128 * 64];
  __shared__ __align__(16) bf16_t Bs[128 * 64];
  f32x4 acc[4][4];
#pragma unroll
  for (int i = 0; i < 4; ++i)
#pragma unroll
    for (int j = 0; j < 4; ++j) acc[i][j] = (f32x4){0.f, 0.f, 0.f, 0.f};

  gemm_core(A, B, NH * DD, 1024, m0, n0, As, Bs, acc);

  const int tid = threadIdx.x, wave = tid >> 6, lane = tid & 63;
  const int l15 = lane & 15, quad = lane >> 4;
  const int wm = (wave & 1) * 64, wn = (wave >> 1) * 64;
#pragma unroll
  for (int i = 0; i < 4; ++i)
#pragma unroll
    for (int j = 0; j < 4; ++j)
#pragma unroll
      for (int r = 0; r < 4; ++r) {
        const int row = m0 + wm + i * 16 + quad * 4 + r;
        const int col = n0 + wn + j * 16 + l15;
        P[(size_t)row * DD + col] = acc[i][j][r];
      }
}

__global__ void reduce_out(const float* __restrict__ p, const float* __restrict__ bp,
                           float* __restrict__ out) {
  const int N = B_DIM * LQ * DD;
  int i = (blockIdx.x * 256 + threadIdx.x) * 4;
  float4 a = *(const float4*)(p + i);
  float4 b = *(const float4*)(p + N + i);
  float4 c = *(const float4*)(p + 2 * N + i);
  float4 d = *(const float4*)(p + 3 * N + i);
  const float4 bb4 = *(const float4*)(bp + (i & 511));
  float4 r;
  r.x = a.x + b.x + c.x + d.x + bb4.x;
  r.y = a.y + b.y + c.y + d.y + bb4.y;
  r.z = a.z + b.z + c.z + d.z + bb4.z;
  r.w = a.w + b.w + c.w + d.w + bb4.w;
  *(float4*)(out + i) = r;
}

// ---------------- host launcher ----------------
extern "C" void kernel_launch(void* const* d_in, const int* in_sizes, int n_in,
                              void* d_out, int out_size, void* d_ws, size_t ws_size,
                              hipStream_t stream) {
  const float* x      = (const float*)d_in[0];
  const float* states = (const float*)d_in[1];
  const int*   mask   = (const int*)d_in[2];
  const float* Wq     = (const float*)d_in[3];
  const float* bq     = (const float*)d_in[4];
  const float* Wk     = (const float*)d_in[5];
  const float* bk     = (const float*)d_in[6];
  const float* Wv     = (const float*)d_in[7];
  const float* bv     = (const float*)d_in[8];
  const float* Wp     = (const float*)d_in[9];
  const float* bp     = (const float*)d_in[10];
  float* out = (float*)d_out;

  // Workspace layout (160 MiB, proven safe):
  //   ctx 64MB @ 0 ; bf16 x 8MB @ 48M, states 8MB @ 56M (chunk-3 overlay,
  //     read by qkv(3) before pv(3) writes that ctx region)
  //   wqb/wkb/wvb 4MB each @ 64M..76M
  //   Qc 16MB @ 76M ; Kc 16MB @ 92M ; Vtc 16MB @ 108M ; S 32MB @ 124M
  //   out-proj fp32 partials (64MB) reuse Kc/Vtc/S after chunks
  // d_out scratch: rowsum 1MB @0 ; mask-int8 8MB @1M ; wpb 4MB @9M
  char* ws = (char*)d_ws;
  bf16_t* ctxb = (bf16_t*)(ws + 0);
  bf16_t* xbF  = (bf16_t*)(ws + 50331648);   // 48 MiB
  bf16_t* sbF  = (bf16_t*)(ws + 58720256);   // 56 MiB
  bf16_t* wqb  = (bf16_t*)(ws + 67108864);
  bf16_t* wkb  = (bf16_t*)(ws + 71303168);
  bf16_t* wvb  = (bf16_t*)(ws + 75497472);
  bf16_t* Qc   = (bf16_t*)(ws + 79691776);
  bf16_t* Kc   = (bf16_t*)(ws + 96468992);
  bf16_t* Vtc  = (bf16_t*)(ws + 113246208);
  bf16_t* Sb   = (bf16_t*)(ws + 130023424);
  float*  pbuf = (float*)(ws + 96468992);    // dead Kc/Vtc/S region after chunks
  float*  rsum = out;                                     // 1MB @ d_out+0
  unsigned char* mkb = (unsigned char*)out + (1 << 20);   // 8MB @ d_out+1M
  bf16_t* wpb  = (bf16_t*)((char*)out + 9 * (1 << 20));   // 4MB @ d_out+9M

  const int n_xc = LB * LQ * DD;         // 1,048,576 elements per chunk

  // one upfront conversion dispatch: 6,291,456 groups -> 24576 blocks
  cvt_all<<<24576, 256, 0, stream>>>(Wq, Wk, Wv, Wp, x, states, mask,
                                     wqb, wkb, wvb, wpb, xbF, sbF, mkb);

  // fused chunk loop (cooperative).  Falls back to split dispatches if the
  // cooperative launch is rejected (e.g. capture/runtime unsupported).
  {
    const bf16_t* a_xbF = xbF; const bf16_t* a_sbF = sbF;
    const bf16_t* a_wq = wqb;  const bf16_t* a_wk = wkb; const bf16_t* a_wv = wvb;
    const float* a_bq = bq;    const float* a_bk = bk;   const float* a_bv = bv;
    const unsigned char* a_mk = mkb;
    bf16_t* a_Qc = Qc; bf16_t* a_Kc = Kc; bf16_t* a_Vt = Vtc; bf16_t* a_Sb = Sb;
    float* a_rs = rsum; bf16_t* a_ctx = ctxb;
    void* args[] = {&a_xbF, &a_sbF, &a_wq, &a_wk, &a_wv, &a_bq, &a_bk, &a_bv,
                    &a_mk, &a_Qc, &a_Kc, &a_Vt, &a_Sb, &a_rs, &a_ctx};
    hipError_t e = hipLaunchCooperativeKernel(
        (const void*)fused_chunks, dim3(1024), dim3(256), args, 0u, stream);
    if (e != hipSuccess) {
      (void)hipGetLastError();   // clear sticky error, use fallback path
      for (int c = 0; c < NCH; ++c) {
        const bf16_t* xc = xbF + (size_t)c * n_xc;
        const bf16_t* sc = sbF + (size_t)c * n_xc;
        const unsigned char* mc = mkb + (size_t)c * LB * LQ * LK;
        bf16_t* ctxc = ctxb + (size_t)c * LB * LQ * (NH * DD);
        gemm_qkv<<<dim3(32, 3 * LB * NH), 256, 0, stream>>>(
            xc, sc, wqb, wkb, wvb, bq, bk, bv, Qc, Kc, Vtc);
        gemm_qk<<<dim3(8, 8, LB * NH), 256, 0, stream>>>(Qc, Kc, mc, Sb, rsum);
        gemm_pv<<<dim3(8, 4, LB * NH), 256, 0, stream>>>(Sb, Vtc, rsum, ctxc);
      }
    }
  }

  // out = ctx @ Wp^T + bp : split-K=4 (1024 blocks) + reduce
  gemm_outk<<<dim3(64, 4, 4), 256, 0, stream>>>(ctxb, wpb, pbuf);
  reduce_out<<<(B_DIM * LQ * DD) / 1024, 256, 0, stream>>>(pbuf, bp, out);
}

// Round 7
// 528.881 us; speedup vs baseline: 4.4783x; 4.4783x over previous
//
#include <hip/hip_runtime.h>
#include <hip/hip_bf16.h>

typedef __bf16 bf16_t;
typedef __bf16 bf16x8 __attribute__((ext_vector_type(8)));
typedef float f32x4 __attribute__((ext_vector_type(4)));

#define B_DIM 8
#define LQ 1024
#define LK 1024
#define DD 512
#define NH 8
#define LB 2          // batches per chunk
#define NCH 4         // chunks

static __device__ __forceinline__ f32x4 mfma_bf16(bf16x8 a, bf16x8 b, f32x4 c) {
  return __builtin_amdgcn_mfma_f32_16x16x32_bf16(a, b, c, 0, 0, 0);
}

// async global->LDS, 16B per lane (wave-uniform LDS base + lane*16)
static __device__ __forceinline__ void gld_lds16(const bf16_t* g, bf16_t* l) {
  __builtin_amdgcn_global_load_lds(
      (const __attribute__((address_space(1))) void*)g,
      (__attribute__((address_space(3))) void*)l, 16, 0, 0);
}

// XCD-aware chunked swizzle (T1).  NOT applied to gemm_outk (R4: natural
// mapping already co-locates A-strip siblings; swizzle doubled FETCH).
// R6 lesson: do NOT replace dispatch boundaries with grid.sync() — on 8
// non-coherent XCD L2s each sync forces a device-wide flush (measured:
// 485 GB/s, MfmaUtil 4.4%, 4.4x slowdown).
static __device__ __forceinline__ int xcd_swz(int lin, int nwg) {
  return (lin & 7) * (nwg >> 3) + (lin >> 3);
}

// ---------------- one upfront conversion kernel ----------------
// Flattened 1D grid over float4/int4 groups:
//   [0, 2M)  : 4 weight matrices fp32->bf16 ; [2M, 4M) : x then states ;
//   [4M, 6M) : mask int32->int8.
__global__ void cvt_all(
    const float* __restrict__ Wq, const float* __restrict__ Wk,
    const float* __restrict__ Wv, const float* __restrict__ Wp,
    const float* __restrict__ x, const float* __restrict__ st,
    const int* __restrict__ mask,
    bf16_t* __restrict__ wqb, bf16_t* __restrict__ wkb,
    bf16_t* __restrict__ wvb, bf16_t* __restrict__ wpb,
    bf16_t* __restrict__ xb, bf16_t* __restrict__ sb,
    unsigned char* __restrict__ mkb)
{
  const int g = blockIdx.x * 256 + threadIdx.x;
  if (g < 2097152) {                       // weights
    const int w = g >> 19;
    const int i = (g & 524287) * 4;
    const float* s4 = (w == 0) ? Wq : (w == 1) ? Wk : (w == 2) ? Wv : Wp;
    bf16_t* d = (w == 0) ? wqb : (w == 1) ? wkb : (w == 2) ? wvb : wpb;
    const float4 f = *(const float4*)(s4 + i);
    bf16_t* p = d + i;
    p[0] = (bf16_t)f.x; p[1] = (bf16_t)f.y; p[2] = (bf16_t)f.z; p[3] = (bf16_t)f.w;
  } else if (g < 4194304) {                // x / states
    const int h = g - 2097152;
    const int i = (h & 1048575) * 4;
    const float* s4 = (h >> 20) ? st : x;
    bf16_t* d = (h >> 20) ? sb : xb;
    const float4 f = *(const float4*)(s4 + i);
    bf16_t* p = d + i;
    p[0] = (bf16_t)f.x; p[1] = (bf16_t)f.y; p[2] = (bf16_t)f.z; p[3] = (bf16_t)f.w;
  } else {                                 // mask
    const int i = (g - 4194304) * 4;
    const int4 v = *(const int4*)(mask + i);
    uchar4 o;
    o.x = (unsigned char)v.x; o.y = (unsigned char)v.y;
    o.z = (unsigned char)v.z; o.w = (unsigned char)v.w;
    *(uchar4*)(mkb + i) = o;
  }
}

// ---------------- GEMM mainloop: BK=64, XOR-swizzled LDS ----------------
// C-tile 128x128, BK=64 (32 MFMA per barrier-pair), global_load_lds width-16.
// LDS layout: slot s in [0,1024) holds row r=s>>3, global col-chunk (s&7)^(r&7).
static __device__ __forceinline__ void gemm_core(
    const bf16_t* __restrict__ A, const bf16_t* __restrict__ B, int ld, int klen,
    int m0, int n0, bf16_t* As, bf16_t* Bs, f32x4 (&acc)[4][4])
{
  const int tid = threadIdx.x;
  const int wave = tid >> 6, lane = tid & 63;
  const int l15 = lane & 15, quad = lane >> 4;
  const int wm = (wave & 1) * 64, wn = (wave >> 1) * 64;

  const int r0 = tid >> 3;        // + p*32 per pass
  const int c8s = tid & 7;        // stored chunk index
  bf16_t* Asl = As + tid * 8;
  bf16_t* Bsl = Bs + tid * 8;

  for (int k0 = 0; k0 < klen; k0 += 64) {
    __syncthreads();
#pragma unroll
    for (int p = 0; p < 4; ++p) {
      const int r = r0 + p * 32;
      const int gc = ((c8s ^ (r & 7)) * 8) + k0;
      gld_lds16(A + (size_t)(m0 + r) * ld + gc, Asl + p * 2048);
      gld_lds16(B + (size_t)(n0 + r) * ld + gc, Bsl + p * 2048);
    }
    __syncthreads();  // drains vmcnt
#pragma unroll
    for (int ks = 0; ks < 2; ++ks) {
      bf16x8 af[4], bfr[4];
#pragma unroll
      for (int i = 0; i < 4; ++i) {
        const int r = wm + i * 16 + l15;
        af[i] = *(const bf16x8*)&As[(r * 8 + ((ks * 4 + quad) ^ (r & 7))) * 8];
      }
#pragma unroll
      for (int j = 0; j < 4; ++j) {
        const int r = wn + j * 16 + l15;
        bfr[j] = *(const bf16x8*)&Bs[(r * 8 + ((ks * 4 + quad) ^ (r & 7))) * 8];
      }
#pragma unroll
      for (int i = 0; i < 4; ++i)
#pragma unroll
        for (int j = 0; j < 4; ++j)
          acc[i][j] = mfma_bf16(af[i], bfr[j], acc[i][j]);
    }
  }
}

// ---------------- fused Q/K/Vt projections ----------------
// grid (32, 3*LB*NH) = 1536 blocks; xcd_swz: each XCD owns 6 complete
// (role,z) groups (32 blocks sharing a 2MB weight+input set).
__global__ __launch_bounds__(256, 4) void gemm_qkv(
    const bf16_t* __restrict__ xcb, const bf16_t* __restrict__ scb,
    const bf16_t* __restrict__ wq, const bf16_t* __restrict__ wk,
    const bf16_t* __restrict__ wv,
    const float* __restrict__ bq, const float* __restrict__ bk,
    const float* __restrict__ bv,
    bf16_t* __restrict__ Qc, bf16_t* __restrict__ Kc, bf16_t* __restrict__ Vtc)
{
  const int lin = blockIdx.y * 32 + blockIdx.x;
  const int wg = xcd_swz(lin, 32 * 3 * LB * NH);
  const int tx = wg & 31, yy = wg >> 5;
  const int role = yy >> 4, z = yy & 15;
  const int bb = z >> 3, hh = z & 7;

  const bf16_t* A; const bf16_t* Bm; const float* bias; bf16_t* C;
  int m0, n0, ldc, bias_row;
  if (role == 0) {
    A = xcb + (size_t)bb * LQ * DD; Bm = wq + (size_t)hh * DD * DD;
    bias = bq + hh * DD; C = Qc + (size_t)z * LQ * DD;
    m0 = (tx >> 2) * 128; n0 = (tx & 3) * 128; ldc = DD; bias_row = 0;
  } else if (role == 1) {
    A = scb + (size_t)bb * LK * DD; Bm = wk + (size_t)hh * DD * DD;
    bias = bk + hh * DD; C = Kc + (size_t)z * LK * DD;
    m0 = (tx >> 2) * 128; n0 = (tx & 3) * 128; ldc = DD; bias_row = 0;
  } else {
    A = wv + (size_t)hh * DD * DD; Bm = scb + (size_t)bb * LK * DD;
    bias = bv + hh * DD; C = Vtc + (size_t)z * DD * LK;
    m0 = (tx & 3) * 128; n0 = (tx >> 2) * 128; ldc = LK; bias_row = 1;
  }

  __shared__ __align__(16) bf16_t As[128 * 64];
  __shared__ __align__(16) bf16_t Bs[128 * 64];
  f32x4 acc[4][4];
#pragma unroll
  for (int i = 0; i < 4; ++i)
#pragma unroll
    for (int j = 0; j < 4; ++j) acc[i][j] = (f32x4){0.f, 0.f, 0.f, 0.f};

  gemm_core(A, Bm, DD, DD, m0, n0, As, Bs, acc);

  const int tid = threadIdx.x, wave = tid >> 6, lane = tid & 63;
  const int l15 = lane & 15, quad = lane >> 4;
  const int wm = (wave & 1) * 64, wn = (wave >> 1) * 64;
#pragma unroll
  for (int i = 0; i < 4; ++i)
#pragma unroll
    for (int j = 0; j < 4; ++j)
#pragma unroll
      for (int r = 0; r < 4; ++r) {
        const int row = m0 + wm + i * 16 + quad * 4 + r;
        const int col = n0 + wn + j * 16 + l15;
        const float v = acc[i][j][r] + (bias_row ? bias[row] : bias[col]);
        C[(size_t)row * ldc + col] = (bf16_t)v;
      }
}

// ---------------- pass 1: S = exp(mask ? QK^T*scale : 0), rowsum partials ----
// grid (8, 8, LB*NH) = 1024 blocks; swizzled -> each XCD owns 2 full z-groups.
// rs layout: [z][ntile(8)][half(2)][LQ] f32.
__global__ __launch_bounds__(256, 4) void gemm_qk(
    const bf16_t* __restrict__ Q, const bf16_t* __restrict__ K,
    const unsigned char* __restrict__ maskb, bf16_t* __restrict__ S,
    float* __restrict__ rs)
{
  const int lin = (blockIdx.z * 8 + blockIdx.y) * 8 + blockIdx.x;
  const int wg = xcd_swz(lin, 8 * 8 * LB * NH);
  const int bx = wg & 7, nt = (wg >> 3) & 7, z = wg >> 6;
  const int bb = z >> 3;
  const bf16_t* Az = Q + (size_t)z * LQ * DD;
  const bf16_t* Bz = K + (size_t)z * LK * DD;
  bf16_t* Sz = S + (size_t)z * LQ * LK;
  const unsigned char* mz = maskb + (size_t)bb * LQ * LK;

  const int m0 = bx * 128, n0 = nt * 128;
  __shared__ __align__(16) bf16_t As[128 * 64];
  __shared__ __align__(16) bf16_t Bs[128 * 64];
  f32x4 acc[4][4];
#pragma unroll
  for (int i = 0; i < 4; ++i)
#pragma unroll
    for (int j = 0; j < 4; ++j) acc[i][j] = (f32x4){0.f, 0.f, 0.f, 0.f};

  gemm_core(Az, Bz, DD, DD, m0, n0, As, Bs, acc);

  const int tid = threadIdx.x, wave = tid >> 6, lane = tid & 63;
  const int l15 = lane & 15, quad = lane >> 4;
  const int wm = (wave & 1) * 64, wn = (wave >> 1) * 64;
  float* rsz = rs + (((size_t)z * 8 + nt) * 2 + (wave >> 1)) * LQ;
  const float scale = 0.04419417382415922f;  // 1/sqrt(512)

#pragma unroll
  for (int i = 0; i < 4; ++i)
#pragma unroll
    for (int r = 0; r < 4; ++r) {
      const int row = m0 + wm + i * 16 + quad * 4 + r;
      float rsum = 0.f;
#pragma unroll
      for (int j = 0; j < 4; ++j) {
        const int col = n0 + wn + j * 16 + l15;
        const int mv = mz[(size_t)row * LK + col];
        const float p = mv ? __expf(acc[i][j][r] * scale) : 0.f;
        rsum += p;
        Sz[(size_t)row * LK + col] = (bf16_t)p;
      }
      rsum += __shfl_xor(rsum, 1);
      rsum += __shfl_xor(rsum, 2);
      rsum += __shfl_xor(rsum, 4);
      rsum += __shfl_xor(rsum, 8);
      if (l15 == 0) rsz[row] = rsum;   // block+half-owned slot, no race
    }
}

// ---------------- pass 2: ctx = (S * inv_rowsum) . V ----------------
// grid (8, 4, LB*NH) = 512 blocks; swizzled -> each XCD owns 2 z-groups.
__global__ __launch_bounds__(256, 4) void gemm_pv(
    const bf16_t* __restrict__ S, const bf16_t* __restrict__ Vt,
    const float* __restrict__ rs, bf16_t* __restrict__ ctx)
{
  const int lin = (blockIdx.z * 4 + blockIdx.y) * 8 + blockIdx.x;
  const int wg = xcd_swz(lin, 8 * 4 * LB * NH);
  const int bx = wg & 7, by = (wg >> 3) & 3, z = wg >> 5;
  const int bb = z >> 3, hh = z & 7;
  const bf16_t* Az = S + (size_t)z * LQ * LK;
  const bf16_t* Bz = Vt + (size_t)z * DD * LK;
  bf16_t* Cz = ctx + (size_t)bb * LQ * (NH * DD) + (size_t)hh * DD;

  const int m0 = bx * 128, n0 = by * 128;
  __shared__ __align__(16) bf16_t As[128 * 64];
  __shared__ __align__(16) bf16_t Bs[128 * 64];
  __shared__ float invs[128];

  const int tid = threadIdx.x;
  if (tid < 128) {   // rowsum reduce for this block's 128 rows
    const float* p = rs + (size_t)z * 16 * LQ + (m0 + tid);
    float tot = 0.f;
#pragma unroll
    for (int s = 0; s < 16; ++s) tot += p[s * LQ];
    invs[tid] = 1.f / tot;
  }
  // visibility guaranteed by gemm_core's internal barriers before epilogue

  f32x4 acc[4][4];
#pragma unroll
  for (int i = 0; i < 4; ++i)
#pragma unroll
    for (int j = 0; j < 4; ++j) acc[i][j] = (f32x4){0.f, 0.f, 0.f, 0.f};

  gemm_core(Az, Bz, LK, LK, m0, n0, As, Bs, acc);

  const int wave = tid >> 6, lane = tid & 63;
  const int l15 = lane & 15, quad = lane >> 4;
  const int wm = (wave & 1) * 64, wn = (wave >> 1) * 64;

#pragma unroll
  for (int i = 0; i < 4; ++i)
#pragma unroll
    for (int r = 0; r < 4; ++r) {
      const int lrow = wm + i * 16 + quad * 4 + r;
      const float iv = invs[lrow];
#pragma unroll
      for (int j = 0; j < 4; ++j) {
        const int col = n0 + wn + j * 16 + l15;
        Cz[(size_t)(m0 + lrow) * (NH * DD) + col] = (bf16_t)(acc[i][j][r] * iv);
      }
    }
}

// ---------------- out init + out-projection (atomic split-K=4) ----------
// init_out: out = bias broadcast.  Runs after pv(3) (all d_out scratch dead).
__global__ void init_out(const float* __restrict__ bp, float* __restrict__ out) {
  int i = (blockIdx.x * 256 + threadIdx.x) * 4;
  *(float4*)(out + i) = *(const float4*)(bp + (i & 511));
}

// grid (64, 4, 4) = 1024 blocks, NATURAL mapping: ks-siblings of a (bx,by)
// tile are at lin stride 256 -> same XCD -> atomics resolve in local L2.
// Epilogue: hardware f32 atomic add into out (replaces fp32 partials +
// reduce_out dispatch: -64MB partial write, -64MB read, -1 dispatch).
__global__ __launch_bounds__(256, 4) void gemm_outk(
    const bf16_t* __restrict__ ctx, const bf16_t* __restrict__ wp,
    float* __restrict__ out)
{
  const int ks = blockIdx.z;
  const bf16_t* A = ctx + ks * 1024;
  const bf16_t* B = wp + ks * 1024;

  const int m0 = blockIdx.x * 128, n0 = blockIdx.y * 128;
  __shared__ __align__(16) bf16_t As[128 * 64];
  __shared__ __align__(16) bf16_t Bs[128 * 64];
  f32x4 acc[4][4];
#pragma unroll
  for (int i = 0; i < 4; ++i)
#pragma unroll
    for (int j = 0; j < 4; ++j) acc[i][j] = (f32x4){0.f, 0.f, 0.f, 0.f};

  gemm_core(A, B, NH * DD, 1024, m0, n0, As, Bs, acc);

  const int tid = threadIdx.x, wave = tid >> 6, lane = tid & 63;
  const int l15 = lane & 15, quad = lane >> 4;
  const int wm = (wave & 1) * 64, wn = (wave >> 1) * 64;
#pragma unroll
  for (int i = 0; i < 4; ++i)
#pragma unroll
    for (int j = 0; j < 4; ++j)
#pragma unroll
      for (int r = 0; r < 4; ++r) {
        const int row = m0 + wm + i * 16 + quad * 4 + r;
        const int col = n0 + wn + j * 16 + l15;
        unsafeAtomicAdd(&out[(size_t)row * DD + col], acc[i][j][r]);
      }
}

// ---------------- host launcher ----------------
extern "C" void kernel_launch(void* const* d_in, const int* in_sizes, int n_in,
                              void* d_out, int out_size, void* d_ws, size_t ws_size,
                              hipStream_t stream) {
  const float* x      = (const float*)d_in[0];
  const float* states = (const float*)d_in[1];
  const int*   mask   = (const int*)d_in[2];
  const float* Wq     = (const float*)d_in[3];
  const float* bq     = (const float*)d_in[4];
  const float* Wk     = (const float*)d_in[5];
  const float* bk     = (const float*)d_in[6];
  const float* Wv     = (const float*)d_in[7];
  const float* bv     = (const float*)d_in[8];
  const float* Wp     = (const float*)d_in[9];
  const float* bp     = (const float*)d_in[10];
  float* out = (float*)d_out;

  // Workspace layout (160 MiB):
  //   ctx 64MB @ 0 ; bf16 x 8MB @ 48M, states 8MB @ 56M (chunk-3 overlay,
  //     read by qkv(3) before pv(3) writes that ctx region)
  //   wqb/wkb/wvb 4MB each @ 64M..76M
  //   Qc 16MB @ 76M ; Kc 16MB @ 92M ; Vtc 16MB @ 108M ; S 32MB @ 124M
  //   wpb 4MB @ 156M (free region; must survive into gemm_outk)
  // d_out (16MB) scratch, all dead before init_out:
  //   rowsum partials 1MB @ 0 (dead after pv(3)) ; mask-int8 8MB @ 1M
  //   (dead after qk(3))
  char* ws = (char*)d_ws;
  bf16_t* ctxb = (bf16_t*)(ws + 0);
  bf16_t* xbF  = (bf16_t*)(ws + 50331648);   // 48 MiB
  bf16_t* sbF  = (bf16_t*)(ws + 58720256);   // 56 MiB
  bf16_t* wqb  = (bf16_t*)(ws + 67108864);
  bf16_t* wkb  = (bf16_t*)(ws + 71303168);
  bf16_t* wvb  = (bf16_t*)(ws + 75497472);
  bf16_t* Qc   = (bf16_t*)(ws + 79691776);
  bf16_t* Kc   = (bf16_t*)(ws + 96468992);
  bf16_t* Vtc  = (bf16_t*)(ws + 113246208);
  bf16_t* Sb   = (bf16_t*)(ws + 130023424);
  bf16_t* wpb  = (bf16_t*)(ws + 163577856);  // 156 MiB (ends at 160 MiB)
  float*  rsum = out;                                     // 1MB @ d_out+0
  unsigned char* mkb = (unsigned char*)out + (1 << 20);   // 8MB @ d_out+1M

  const int n_xc = LB * LQ * DD;         // 1,048,576 elements per chunk

  // one upfront conversion dispatch: 6,291,456 groups -> 24576 blocks
  cvt_all<<<24576, 256, 0, stream>>>(Wq, Wk, Wv, Wp, x, states, mask,
                                     wqb, wkb, wvb, wpb, xbF, sbF, mkb);

  for (int c = 0; c < NCH; ++c) {
    const bf16_t* xc = xbF + (size_t)c * n_xc;
    const bf16_t* sc = sbF + (size_t)c * n_xc;
    const unsigned char* mc = mkb + (size_t)c * LB * LQ * LK;
    bf16_t* ctxc = ctxb + (size_t)c * LB * LQ * (NH * DD);

    // fused Q/K/Vt projections: 1536 blocks = 6 blocks/CU
    gemm_qkv<<<dim3(32, 3 * LB * NH), 256, 0, stream>>>(
        xc, sc, wqb, wkb, wvb, bq, bk, bv, Qc, Kc, Vtc);

    // attention as two GEMM passes
    gemm_qk<<<dim3(8, 8, LB * NH), 256, 0, stream>>>(Qc, Kc, mc, Sb, rsum);
    gemm_pv<<<dim3(8, 4, LB * NH), 256, 0, stream>>>(Sb, Vtc, rsum, ctxc);
  }

  // out = bias; then ctx @ Wp^T accumulated atomically (split-K=4)
  init_out<<<(B_DIM * LQ * DD) / 1024, 256, 0, stream>>>(bp, out);
  gemm_outk<<<dim3(64, 4, 4), 256, 0, stream>>>(ctxb, wpb, out);
}

// Round 8
// 528.357 us; speedup vs baseline: 4.4827x; 1.0010x over previous
//
#include <hip/hip_runtime.h>
#include <hip/hip_bf16.h>

typedef __bf16 bf16_t;
typedef __bf16 bf16x8 __attribute__((ext_vector_type(8)));
typedef float f32x4 __attribute__((ext_vector_type(4)));

#define B_DIM 8
#define LQ 1024
#define LK 1024
#define DD 512
#define NH 8
#define LB 2          // batches per chunk
#define NCH 4         // chunks

static __device__ __forceinline__ f32x4 mfma_bf16(bf16x8 a, bf16x8 b, f32x4 c) {
  return __builtin_amdgcn_mfma_f32_16x16x32_bf16(a, b, c, 0, 0, 0);
}

// async global->LDS, 16B per lane (wave-uniform LDS base + lane*16)
static __device__ __forceinline__ void gld_lds16(const bf16_t* g, bf16_t* l) {
  __builtin_amdgcn_global_load_lds(
      (const __attribute__((address_space(1))) void*)g,
      (__attribute__((address_space(3))) void*)l, 16, 0, 0);
}

// XCD-aware chunked swizzle (T1).  NOT applied to gemm_outk (R4: natural
// mapping already co-locates A-strip siblings; swizzle doubled FETCH).
// R6 lesson: grid.sync() forces device-wide L2 flush on 8 non-coherent XCDs
// (4.4x slowdown).  R7 lesson: atomic split-K epilogue serializes on L2 RMW
// (outk 41->74us) — plain partials+reduce wins.
static __device__ __forceinline__ int xcd_swz(int lin, int nwg) {
  return (lin & 7) * (nwg >> 3) + (lin >> 3);
}

// ---------------- one upfront conversion kernel ----------------
// Flattened 1D grid over float4/int4 groups:
//   [0, 2M)  : 4 weight matrices fp32->bf16 ; [2M, 4M) : x then states ;
//   [4M, 6M) : mask int32->int8.
__global__ void cvt_all(
    const float* __restrict__ Wq, const float* __restrict__ Wk,
    const float* __restrict__ Wv, const float* __restrict__ Wp,
    const float* __restrict__ x, const float* __restrict__ st,
    const int* __restrict__ mask,
    bf16_t* __restrict__ wqb, bf16_t* __restrict__ wkb,
    bf16_t* __restrict__ wvb, bf16_t* __restrict__ wpb,
    bf16_t* __restrict__ xb, bf16_t* __restrict__ sb,
    unsigned char* __restrict__ mkb)
{
  const int g = blockIdx.x * 256 + threadIdx.x;
  if (g < 2097152) {                       // weights
    const int w = g >> 19;
    const int i = (g & 524287) * 4;
    const float* s4 = (w == 0) ? Wq : (w == 1) ? Wk : (w == 2) ? Wv : Wp;
    bf16_t* d = (w == 0) ? wqb : (w == 1) ? wkb : (w == 2) ? wvb : wpb;
    const float4 f = *(const float4*)(s4 + i);
    bf16_t* p = d + i;
    p[0] = (bf16_t)f.x; p[1] = (bf16_t)f.y; p[2] = (bf16_t)f.z; p[3] = (bf16_t)f.w;
  } else if (g < 4194304) {                // x / states
    const int h = g - 2097152;
    const int i = (h & 1048575) * 4;
    const float* s4 = (h >> 20) ? st : x;
    bf16_t* d = (h >> 20) ? sb : xb;
    const float4 f = *(const float4*)(s4 + i);
    bf16_t* p = d + i;
    p[0] = (bf16_t)f.x; p[1] = (bf16_t)f.y; p[2] = (bf16_t)f.z; p[3] = (bf16_t)f.w;
  } else {                                 // mask
    const int i = (g - 4194304) * 4;
    const int4 v = *(const int4*)(mask + i);
    uchar4 o;
    o.x = (unsigned char)v.x; o.y = (unsigned char)v.y;
    o.z = (unsigned char)v.z; o.w = (unsigned char)v.w;
    *(uchar4*)(mkb + i) = o;
  }
}

// ---------------- GEMM mainloop: 128x128, BK=64, XOR-swizzled LDS --------
// LDS layout: slot s in [0,1024) holds row r=s>>3, global col-chunk (s&7)^(r&7).
static __device__ __forceinline__ void gemm_core(
    const bf16_t* __restrict__ A, const bf16_t* __restrict__ B, int ld, int klen,
    int m0, int n0, bf16_t* As, bf16_t* Bs, f32x4 (&acc)[4][4])
{
  const int tid = threadIdx.x;
  const int wave = tid >> 6, lane = tid & 63;
  const int l15 = lane & 15, quad = lane >> 4;
  const int wm = (wave & 1) * 64, wn = (wave >> 1) * 64;

  const int r0 = tid >> 3;        // + p*32 per pass
  const int c8s = tid & 7;        // stored chunk index
  bf16_t* Asl = As + tid * 8;
  bf16_t* Bsl = Bs + tid * 8;

  for (int k0 = 0; k0 < klen; k0 += 64) {
    __syncthreads();
#pragma unroll
    for (int p = 0; p < 4; ++p) {
      const int r = r0 + p * 32;
      const int gc = ((c8s ^ (r & 7)) * 8) + k0;
      gld_lds16(A + (size_t)(m0 + r) * ld + gc, Asl + p * 2048);
      gld_lds16(B + (size_t)(n0 + r) * ld + gc, Bsl + p * 2048);
    }
    __syncthreads();  // drains vmcnt
#pragma unroll
    for (int ks = 0; ks < 2; ++ks) {
      bf16x8 af[4], bfr[4];
#pragma unroll
      for (int i = 0; i < 4; ++i) {
        const int r = wm + i * 16 + l15;
        af[i] = *(const bf16x8*)&As[(r * 8 + ((ks * 4 + quad) ^ (r & 7))) * 8];
      }
#pragma unroll
      for (int j = 0; j < 4; ++j) {
        const int r = wn + j * 16 + l15;
        bfr[j] = *(const bf16x8*)&Bs[(r * 8 + ((ks * 4 + quad) ^ (r & 7))) * 8];
      }
#pragma unroll
      for (int i = 0; i < 4; ++i)
#pragma unroll
        for (int j = 0; j < 4; ++j)
          acc[i][j] = mfma_bf16(af[i], bfr[j], acc[i][j]);
    }
  }
}

// ---------------- GEMM mainloop variant: 64x128 tile (for gemm_pv) -------
// 4 waves side-by-side (each 64 rows x 32 cols), acc[4][2].  LDS 24KB
// (As 64x64 = 8KB, Bs 128x64 = 16KB) -> 4-6 blocks/CU vs 2 for the 128^2
// core at pv's 512-block grid.  Same XOR-chunk slot formulas; A staged in
// 2 passes, B in 4.
static __device__ __forceinline__ void gemm_core64(
    const bf16_t* __restrict__ A, const bf16_t* __restrict__ B, int ld, int klen,
    int m0, int n0, bf16_t* As, bf16_t* Bs, f32x4 (&acc)[4][2])
{
  const int tid = threadIdx.x;
  const int wave = tid >> 6, lane = tid & 63;
  const int l15 = lane & 15, quad = lane >> 4;
  const int wn = wave * 32;

  const int r0 = tid >> 3;        // + p*32 per pass
  const int c8s = tid & 7;
  bf16_t* Asl = As + tid * 8;
  bf16_t* Bsl = Bs + tid * 8;

  for (int k0 = 0; k0 < klen; k0 += 64) {
    __syncthreads();
#pragma unroll
    for (int p = 0; p < 2; ++p) {       // A: 64 rows
      const int r = r0 + p * 32;
      const int gc = ((c8s ^ (r & 7)) * 8) + k0;
      gld_lds16(A + (size_t)(m0 + r) * ld + gc, Asl + p * 2048);
    }
#pragma unroll
    for (int p = 0; p < 4; ++p) {       // B: 128 rows
      const int r = r0 + p * 32;
      const int gc = ((c8s ^ (r & 7)) * 8) + k0;
      gld_lds16(B + (size_t)(n0 + r) * ld + gc, Bsl + p * 2048);
    }
    __syncthreads();  // drains vmcnt
#pragma unroll
    for (int ks = 0; ks < 2; ++ks) {
      bf16x8 af[4], bfr[2];
#pragma unroll
      for (int i = 0; i < 4; ++i) {
        const int r = i * 16 + l15;
        af[i] = *(const bf16x8*)&As[(r * 8 + ((ks * 4 + quad) ^ (r & 7))) * 8];
      }
#pragma unroll
      for (int j = 0; j < 2; ++j) {
        const int r = wn + j * 16 + l15;
        bfr[j] = *(const bf16x8*)&Bs[(r * 8 + ((ks * 4 + quad) ^ (r & 7))) * 8];
      }
#pragma unroll
      for (int i = 0; i < 4; ++i)
#pragma unroll
        for (int j = 0; j < 2; ++j)
          acc[i][j] = mfma_bf16(af[i], bfr[j], acc[i][j]);
    }
  }
}

// ---------------- fused Q/K/Vt projections ----------------
// grid (32, 3*LB*NH) = 1536 blocks; xcd_swz: each XCD owns 6 complete
// (role,z) groups (32 blocks sharing a 2MB weight+input set).
__global__ __launch_bounds__(256, 4) void gemm_qkv(
    const bf16_t* __restrict__ xcb, const bf16_t* __restrict__ scb,
    const bf16_t* __restrict__ wq, const bf16_t* __restrict__ wk,
    const bf16_t* __restrict__ wv,
    const float* __restrict__ bq, const float* __restrict__ bk,
    const float* __restrict__ bv,
    bf16_t* __restrict__ Qc, bf16_t* __restrict__ Kc, bf16_t* __restrict__ Vtc)
{
  const int lin = blockIdx.y * 32 + blockIdx.x;
  const int wg = xcd_swz(lin, 32 * 3 * LB * NH);
  const int tx = wg & 31, yy = wg >> 5;
  const int role = yy >> 4, z = yy & 15;
  const int bb = z >> 3, hh = z & 7;

  const bf16_t* A; const bf16_t* Bm; const float* bias; bf16_t* C;
  int m0, n0, ldc, bias_row;
  if (role == 0) {
    A = xcb + (size_t)bb * LQ * DD; Bm = wq + (size_t)hh * DD * DD;
    bias = bq + hh * DD; C = Qc + (size_t)z * LQ * DD;
    m0 = (tx >> 2) * 128; n0 = (tx & 3) * 128; ldc = DD; bias_row = 0;
  } else if (role == 1) {
    A = scb + (size_t)bb * LK * DD; Bm = wk + (size_t)hh * DD * DD;
    bias = bk + hh * DD; C = Kc + (size_t)z * LK * DD;
    m0 = (tx >> 2) * 128; n0 = (tx & 3) * 128; ldc = DD; bias_row = 0;
  } else {
    A = wv + (size_t)hh * DD * DD; Bm = scb + (size_t)bb * LK * DD;
    bias = bv + hh * DD; C = Vtc + (size_t)z * DD * LK;
    m0 = (tx & 3) * 128; n0 = (tx >> 2) * 128; ldc = LK; bias_row = 1;
  }

  __shared__ __align__(16) bf16_t As[128 * 64];
  __shared__ __align__(16) bf16_t Bs[128 * 64];
  f32x4 acc[4][4];
#pragma unroll
  for (int i = 0; i < 4; ++i)
#pragma unroll
    for (int j = 0; j < 4; ++j) acc[i][j] = (f32x4){0.f, 0.f, 0.f, 0.f};

  gemm_core(A, Bm, DD, DD, m0, n0, As, Bs, acc);

  const int tid = threadIdx.x, wave = tid >> 6, lane = tid & 63;
  const int l15 = lane & 15, quad = lane >> 4;
  const int wm = (wave & 1) * 64, wn = (wave >> 1) * 64;
#pragma unroll
  for (int i = 0; i < 4; ++i)
#pragma unroll
    for (int j = 0; j < 4; ++j)
#pragma unroll
      for (int r = 0; r < 4; ++r) {
        const int row = m0 + wm + i * 16 + quad * 4 + r;
        const int col = n0 + wn + j * 16 + l15;
        const float v = acc[i][j][r] + (bias_row ? bias[row] : bias[col]);
        C[(size_t)row * ldc + col] = (bf16_t)v;
      }
}

// ---------------- pass 1: S = exp(mask ? QK^T*scale : 0), rowsum partials ----
// grid (8, 8, LB*NH) = 1024 blocks; swizzled -> each XCD owns 2 full z-groups.
// rs layout: [z][ntile(8)][half(2)][LQ] f32.
__global__ __launch_bounds__(256, 4) void gemm_qk(
    const bf16_t* __restrict__ Q, const bf16_t* __restrict__ K,
    const unsigned char* __restrict__ maskb, bf16_t* __restrict__ S,
    float* __restrict__ rs)
{
  const int lin = (blockIdx.z * 8 + blockIdx.y) * 8 + blockIdx.x;
  const int wg = xcd_swz(lin, 8 * 8 * LB * NH);
  const int bx = wg & 7, nt = (wg >> 3) & 7, z = wg >> 6;
  const int bb = z >> 3;
  const bf16_t* Az = Q + (size_t)z * LQ * DD;
  const bf16_t* Bz = K + (size_t)z * LK * DD;
  bf16_t* Sz = S + (size_t)z * LQ * LK;
  const unsigned char* mz = maskb + (size_t)bb * LQ * LK;

  const int m0 = bx * 128, n0 = nt * 128;
  __shared__ __align__(16) bf16_t As[128 * 64];
  __shared__ __align__(16) bf16_t Bs[128 * 64];
  f32x4 acc[4][4];
#pragma unroll
  for (int i = 0; i < 4; ++i)
#pragma unroll
    for (int j = 0; j < 4; ++j) acc[i][j] = (f32x4){0.f, 0.f, 0.f, 0.f};

  gemm_core(Az, Bz, DD, DD, m0, n0, As, Bs, acc);

  const int tid = threadIdx.x, wave = tid >> 6, lane = tid & 63;
  const int l15 = lane & 15, quad = lane >> 4;
  const int wm = (wave & 1) * 64, wn = (wave >> 1) * 64;
  float* rsz = rs + (((size_t)z * 8 + nt) * 2 + (wave >> 1)) * LQ;
  const float scale = 0.04419417382415922f;  // 1/sqrt(512)

#pragma unroll
  for (int i = 0; i < 4; ++i)
#pragma unroll
    for (int r = 0; r < 4; ++r) {
      const int row = m0 + wm + i * 16 + quad * 4 + r;
      float rsum = 0.f;
#pragma unroll
      for (int j = 0; j < 4; ++j) {
        const int col = n0 + wn + j * 16 + l15;
        const int mv = mz[(size_t)row * LK + col];
        const float p = mv ? __expf(acc[i][j][r] * scale) : 0.f;
        rsum += p;
        Sz[(size_t)row * LK + col] = (bf16_t)p;
      }
      rsum += __shfl_xor(rsum, 1);
      rsum += __shfl_xor(rsum, 2);
      rsum += __shfl_xor(rsum, 4);
      rsum += __shfl_xor(rsum, 8);
      if (l15 == 0) rsz[row] = rsum;   // block+half-owned slot, no race
    }
}

// ---------------- pass 2: ctx = (S * inv_rowsum) . V ----------------
// 64x128 tiles: grid (16, 4, LB*NH) = 1024 blocks = 4+/CU (vs 2/CU at 128^2,
// the only under-occupied GEMM).  Swizzled -> each XCD owns 2 z-groups.
__global__ __launch_bounds__(256, 4) void gemm_pv(
    const bf16_t* __restrict__ S, const bf16_t* __restrict__ Vt,
    const float* __restrict__ rs, bf16_t* __restrict__ ctx)
{
  const int lin = (blockIdx.z * 4 + blockIdx.y) * 16 + blockIdx.x;
  const int wg = xcd_swz(lin, 16 * 4 * LB * NH);
  const int bx = wg & 15, by = (wg >> 4) & 3, z = wg >> 6;
  const int bb = z >> 3, hh = z & 7;
  const bf16_t* Az = S + (size_t)z * LQ * LK;
  const bf16_t* Bz = Vt + (size_t)z * DD * LK;
  bf16_t* Cz = ctx + (size_t)bb * LQ * (NH * DD) + (size_t)hh * DD;

  const int m0 = bx * 64, n0 = by * 128;
  __shared__ __align__(16) bf16_t As[64 * 64];
  __shared__ __align__(16) bf16_t Bs[128 * 64];
  __shared__ float invs[64];

  const int tid = threadIdx.x;
  if (tid < 64) {    // rowsum reduce for this block's 64 rows
    const float* p = rs + (size_t)z * 16 * LQ + (m0 + tid);
    float tot = 0.f;
#pragma unroll
    for (int s = 0; s < 16; ++s) tot += p[s * LQ];
    invs[tid] = 1.f / tot;
  }
  // visibility via gemm_core64's internal barriers before epilogue

  f32x4 acc[4][2];
#pragma unroll
  for (int i = 0; i < 4; ++i)
#pragma unroll
    for (int j = 0; j < 2; ++j) acc[i][j] = (f32x4){0.f, 0.f, 0.f, 0.f};

  gemm_core64(Az, Bz, LK, LK, m0, n0, As, Bs, acc);

  const int wave = tid >> 6, lane = tid & 63;
  const int l15 = lane & 15, quad = lane >> 4;
  const int wn = wave * 32;

#pragma unroll
  for (int i = 0; i < 4; ++i)
#pragma unroll
    for (int r = 0; r < 4; ++r) {
      const int lrow = i * 16 + quad * 4 + r;
      const float iv = invs[lrow];
#pragma unroll
      for (int j = 0; j < 2; ++j) {
        const int col = n0 + wn + j * 16 + l15;
        Cz[(size_t)(m0 + lrow) * (NH * DD) + col] = (bf16_t)(acc[i][j][r] * iv);
      }
    }
}

// ---------------- out-projection, split-K=4 (natural mapping) -----------
// grid (64, 4, 4) = 1024 blocks.  R7: atomics regressed (74us); keep
// fp32 partials + reduce (41+13us).
__global__ __launch_bounds__(256, 4) void gemm_outk(
    const bf16_t* __restrict__ ctx, const bf16_t* __restrict__ wp,
    float* __restrict__ partial)
{
  const int ks = blockIdx.z;
  const bf16_t* A = ctx + ks * 1024;
  const bf16_t* B = wp + ks * 1024;
  float* P = partial + (size_t)ks * B_DIM * LQ * DD;

  const int m0 = blockIdx.x * 128, n0 = blockIdx.y * 128;
  __shared__ __align__(16) bf16_t As[128 * 64];
  __shared__ __align__(16) bf16_t Bs[128 * 64];
  f32x4 acc[4][4];
#pragma unroll
  for (int i = 0; i < 4; ++i)
#pragma unroll
    for (int j = 0; j < 4; ++j) acc[i][j] = (f32x4){0.f, 0.f, 0.f, 0.f};

  gemm_core(A, B, NH * DD, 1024, m0, n0, As, Bs, acc);

  const int tid = threadIdx.x, wave = tid >> 6, lane = tid & 63;
  const int l15 = lane & 15, quad = lane >> 4;
  const int wm = (wave & 1) * 64, wn = (wave >> 1) * 64;
#pragma unroll
  for (int i = 0; i < 4; ++i)
#pragma unroll
    for (int j = 0; j < 4; ++j)
#pragma unroll
      for (int r = 0; r < 4; ++r) {
        const int row = m0 + wm + i * 16 + quad * 4 + r;
        const int col = n0 + wn + j * 16 + l15;
        P[(size_t)row * DD + col] = acc[i][j][r];
      }
}

__global__ void reduce_out(const float* __restrict__ p, const float* __restrict__ bp,
                           float* __restrict__ out) {
  const int N = B_DIM * LQ * DD;
  int i = (blockIdx.x * 256 + threadIdx.x) * 4;
  float4 a = *(const float4*)(p + i);
  float4 b = *(const float4*)(p + N + i);
  float4 c = *(const float4*)(p + 2 * N + i);
  float4 d = *(const float4*)(p + 3 * N + i);
  const float4 bb4 = *(const float4*)(bp + (i & 511));
  float4 r;
  r.x = a.x + b.x + c.x + d.x + bb4.x;
  r.y = a.y + b.y + c.y + d.y + bb4.y;
  r.z = a.z + b.z + c.z + d.z + bb4.z;
  r.w = a.w + b.w + c.w + d.w + bb4.w;
  *(float4*)(out + i) = r;
}

// ---------------- host launcher ----------------
extern "C" void kernel_launch(void* const* d_in, const int* in_sizes, int n_in,
                              void* d_out, int out_size, void* d_ws, size_t ws_size,
                              hipStream_t stream) {
  const float* x      = (const float*)d_in[0];
  const float* states = (const float*)d_in[1];
  const int*   mask   = (const int*)d_in[2];
  const float* Wq     = (const float*)d_in[3];
  const float* bq     = (const float*)d_in[4];
  const float* Wk     = (const float*)d_in[5];
  const float* bk     = (const float*)d_in[6];
  const float* Wv     = (const float*)d_in[7];
  const float* bv     = (const float*)d_in[8];
  const float* Wp     = (const float*)d_in[9];
  const float* bp     = (const float*)d_in[10];
  float* out = (float*)d_out;

  // Workspace layout (160 MiB, R5-proven):
  //   ctx 64MB @ 0 ; bf16 x 8MB @ 48M, states 8MB @ 56M (chunk-3 overlay,
  //     read by qkv(3) before pv(3) writes that ctx region)
  //   wqb/wkb/wvb 4MB each @ 64M..76M
  //   Qc 16MB @ 76M ; Kc 16MB @ 92M ; Vtc 16MB @ 108M ; S 32MB @ 124M
  //   out-proj fp32 partials (64MB) reuse Kc/Vtc/S after chunks
  // d_out (16MB) scratch until reduce_out overwrites it:
  //   rowsum partials 1MB @ 0 ; mask-int8 8MB @ 1M ; wpb 4MB @ 9M
  char* ws = (char*)d_ws;
  bf16_t* ctxb = (bf16_t*)(ws + 0);
  bf16_t* xbF  = (bf16_t*)(ws + 50331648);   // 48 MiB
  bf16_t* sbF  = (bf16_t*)(ws + 58720256);   // 56 MiB
  bf16_t* wqb  = (bf16_t*)(ws + 67108864);
  bf16_t* wkb  = (bf16_t*)(ws + 71303168);
  bf16_t* wvb  = (bf16_t*)(ws + 75497472);
  bf16_t* Qc   = (bf16_t*)(ws + 79691776);
  bf16_t* Kc   = (bf16_t*)(ws + 96468992);
  bf16_t* Vtc  = (bf16_t*)(ws + 113246208);
  bf16_t* Sb   = (bf16_t*)(ws + 130023424);
  float*  pbuf = (float*)(ws + 96468992);    // dead Kc/Vtc/S region after chunks
  float*  rsum = out;                                     // 1MB @ d_out+0
  unsigned char* mkb = (unsigned char*)out + (1 << 20);   // 8MB @ d_out+1M
  bf16_t* wpb  = (bf16_t*)((char*)out + 9 * (1 << 20));   // 4MB @ d_out+9M

  const int n_xc = LB * LQ * DD;         // 1,048,576 elements per chunk

  // one upfront conversion dispatch: 6,291,456 groups -> 24576 blocks
  cvt_all<<<24576, 256, 0, stream>>>(Wq, Wk, Wv, Wp, x, states, mask,
                                     wqb, wkb, wvb, wpb, xbF, sbF, mkb);

  for (int c = 0; c < NCH; ++c) {
    const bf16_t* xc = xbF + (size_t)c * n_xc;
    const bf16_t* sc = sbF + (size_t)c * n_xc;
    const unsigned char* mc = mkb + (size_t)c * LB * LQ * LK;
    bf16_t* ctxc = ctxb + (size_t)c * LB * LQ * (NH * DD);

    // fused Q/K/Vt projections: 1536 blocks = 6 blocks/CU
    gemm_qkv<<<dim3(32, 3 * LB * NH), 256, 0, stream>>>(
        xc, sc, wqb, wkb, wvb, bq, bk, bv, Qc, Kc, Vtc);

    // attention as two GEMM passes
    gemm_qk<<<dim3(8, 8, LB * NH), 256, 0, stream>>>(Qc, Kc, mc, Sb, rsum);
    gemm_pv<<<dim3(16, 4, LB * NH), 256, 0, stream>>>(Sb, Vtc, rsum, ctxc);
  }

  // out = ctx @ Wp^T + bp : split-K=4 (1024 blocks) + reduce
  gemm_outk<<<dim3(64, 4, 4), 256, 0, stream>>>(ctxb, wpb, pbuf);
  reduce_out<<<(B_DIM * LQ * DD) / 1024, 256, 0, stream>>>(pbuf, bp, out);
}